// Round 3
// baseline (576.938 us; speedup 1.0000x reference)
//
#include <hip/hip_runtime.h>
#include <cmath>

#define NN 4
#define CC 512
#define SS 6
#define HW_ 4096
#define KK 3072
#define NP_ 16384
#define BN_EPS 1e-5f

// ---------------------------------------------------------------------------
// Prep: pack w_proj [6][3072] -> wT [3072][8] (padded), transpose w_fuse
// [o][c] -> Wt [c][o]. Tiny.
// ---------------------------------------------------------------------------
__global__ __launch_bounds__(256) void kPrep(const float* __restrict__ w_proj,
                                             const float* __restrict__ w_fuse,
                                             float* __restrict__ wT,
                                             float* __restrict__ Wt) {
    const int idx = blockIdx.x * 256 + threadIdx.x;
    if (idx < KK * 8) {
        const int k = idx >> 3, s = idx & 7;
        wT[idx] = (s < SS) ? w_proj[s * KK + k] : 0.0f;
    }
    const int j = idx - KK * 8;
    if (j >= 0 && j < CC * CC) {
        const int c = j >> 9, o = j & 511;
        Wt[j] = w_fuse[o * CC + c];  // Wt[c][o]
    }
}

// ---------------------------------------------------------------------------
// Kernel A: energy[n,s,p] = sum_k cat[n,k,p]*w_proj[s,k] + b_proj[s];
//           att = softmax over s.  Block: 1024 thr = 16 kq-splits x 64 px.
// cat loads lane-coalesced (256B/instr); wT rows via wave-uniform s_loads.
// ---------------------------------------------------------------------------
__global__ __launch_bounds__(1024) void kAtt(const float* __restrict__ cat,
                                             const float* __restrict__ wT,
                                             const float* __restrict__ b_proj,
                                             float* __restrict__ att) {
    __shared__ float red[16][64][6];
    const int tid = threadIdx.x;
    const int px = tid & 63;
    const int kq = __builtin_amdgcn_readfirstlane(tid >> 6);  // 0..15, uniform
    const int pg = blockIdx.x * 64 + px;
    const int n = pg >> 12;
    const int p = pg & 4095;
    const float* cbase = cat + (size_t)n * KK * HW_ + p;

    float e[6] = {0.f, 0.f, 0.f, 0.f, 0.f, 0.f};
    const int k0 = kq * 192;
#pragma unroll 8
    for (int kk = 0; kk < 192; ++kk) {
        const int k = k0 + kk;
        const float v = cbase[(size_t)k * HW_];                      // coalesced
        const float4 wa = *(const float4*)(wT + (size_t)k * 8);      // s_load
        const float2 wb = *(const float2*)(wT + (size_t)k * 8 + 4);  // s_load
        e[0] = fmaf(wa.x, v, e[0]);
        e[1] = fmaf(wa.y, v, e[1]);
        e[2] = fmaf(wa.z, v, e[2]);
        e[3] = fmaf(wa.w, v, e[3]);
        e[4] = fmaf(wb.x, v, e[4]);
        e[5] = fmaf(wb.y, v, e[5]);
    }
#pragma unroll
    for (int s = 0; s < 6; ++s) red[kq][px][s] = e[s];
    __syncthreads();

    if (tid < 64) {
        float t[6];
#pragma unroll
        for (int s = 0; s < 6; ++s) t[s] = b_proj[s];
#pragma unroll
        for (int q = 0; q < 16; ++q)
#pragma unroll
            for (int s = 0; s < 6; ++s) t[s] += red[q][tid][s];
        float m = t[0];
#pragma unroll
        for (int s = 1; s < 6; ++s) m = fmaxf(m, t[s]);
        float ex[6];
        float sum = 0.f;
#pragma unroll
        for (int s = 0; s < 6; ++s) { ex[s] = expf(t[s] - m); sum += ex[s]; }
        const float inv = 1.0f / sum;
#pragma unroll
        for (int s = 0; s < 6; ++s)
            att[((size_t)n * 6 + s) * HW_ + p] = ex[s] * inv;  // [n][s][hw]
    }
}

// ---------------------------------------------------------------------------
// Kernel B: per pixel p:
//   pass1: o (transient) = sum_s yv[c][s]*a1[s];  e2[s] += yv[c][s]*o
//   softmax(e2) -> a2;  ab[s] = a1[s] + gamma*a2[s]
//   pass2: mid[n][c][p] = sum_s yv[c][s]*ab[s]
// (identity: gamma*out2 + out1 = sum_s yv*(a1 + gamma*attn2) — no o1[] regs.)
// Block: 256 thr = 8 cq-splits x 32 px; each thread owns 64 c's.
// ---------------------------------------------------------------------------
__global__ __launch_bounds__(256) void kAggr(const float* __restrict__ stack,
                                             const float* __restrict__ att,
                                             const float* __restrict__ gamma,
                                             float* __restrict__ mid) {
    __shared__ float red2[8][32][6];
    __shared__ float ab_s[32][6];
    const int tid = threadIdx.x;
    const int px = tid & 31;
    const int cq = tid >> 5;  // 0..7
    const int pg = blockIdx.x * 32 + px;
    const int n = pg >> 12;
    const int p = pg & 4095;

    float a1[6];
#pragma unroll
    for (int s = 0; s < 6; ++s) a1[s] = att[((size_t)n * 6 + s) * HW_ + p];

    const float* sb = stack + ((size_t)(n * CC + cq * 64) * HW_ + p) * SS;

    float e2[6] = {0.f, 0.f, 0.f, 0.f, 0.f, 0.f};
#pragma unroll 4
    for (int i = 0; i < 64; ++i) {
        const float2* b2 = (const float2*)(sb + (size_t)i * (HW_ * SS));
        const float2 v01 = b2[0];
        const float2 v23 = b2[1];
        const float2 v45 = b2[2];
        float o = v01.x * a1[0];
        o = fmaf(v01.y, a1[1], o);
        o = fmaf(v23.x, a1[2], o);
        o = fmaf(v23.y, a1[3], o);
        o = fmaf(v45.x, a1[4], o);
        o = fmaf(v45.y, a1[5], o);
        e2[0] = fmaf(v01.x, o, e2[0]);
        e2[1] = fmaf(v01.y, o, e2[1]);
        e2[2] = fmaf(v23.x, o, e2[2]);
        e2[3] = fmaf(v23.y, o, e2[3]);
        e2[4] = fmaf(v45.x, o, e2[4]);
        e2[5] = fmaf(v45.y, o, e2[5]);
    }
#pragma unroll
    for (int s = 0; s < 6; ++s) red2[cq][px][s] = e2[s];
    __syncthreads();

    if (tid < 32) {
        float t[6];
#pragma unroll
        for (int s = 0; s < 6; ++s) t[s] = 0.f;
#pragma unroll
        for (int q = 0; q < 8; ++q)
#pragma unroll
            for (int s = 0; s < 6; ++s) t[s] += red2[q][tid][s];
        float m = t[0];
#pragma unroll
        for (int s = 1; s < 6; ++s) m = fmaxf(m, t[s]);
        float ex[6];
        float sum = 0.f;
#pragma unroll
        for (int s = 0; s < 6; ++s) { ex[s] = expf(t[s] - m); sum += ex[s]; }
        const float inv = gamma[0] / sum;  // fold gamma into a2
        // ab[s] = a1[s] + gamma*attn2[s]; this thread's a1 is for pixel px=tid
#pragma unroll
        for (int s = 0; s < 6; ++s) ab_s[tid][s] = fmaf(ex[s], inv, a1[s]);
    }
    __syncthreads();

    float ab[6];
#pragma unroll
    for (int s = 0; s < 6; ++s) ab[s] = ab_s[px][s];

    float* mb = mid + (size_t)(n * CC + cq * 64) * HW_ + p;
#pragma unroll 4
    for (int i = 0; i < 64; ++i) {
        const float2* b2 = (const float2*)(sb + (size_t)i * (HW_ * SS));
        const float2 v01 = b2[0];
        const float2 v23 = b2[1];
        const float2 v45 = b2[2];
        float o = v01.x * ab[0];
        o = fmaf(v01.y, ab[1], o);
        o = fmaf(v23.x, ab[2], o);
        o = fmaf(v23.y, ab[3], o);
        o = fmaf(v45.x, ab[4], o);
        o = fmaf(v45.y, ab[5], o);
        mb[(size_t)i * HW_] = o;  // coalesced across px lanes
    }
}

// ---------------------------------------------------------------------------
// Kernel C: out[n][o][p] = relu( (sum_c mid[n][c][p]*W[o][c]) * inv[o] + b2[o] )
// f32 GEMM, LDS-free: weight rows via wave-uniform s_loads (Wt[c][o], 32
// SGPR floats/c, unroll 2 => 64 weight SGPRs < 102 budget); mid coalesced
// v-loads (L2/L3 resident, 4x reuse across blockIdx.y).
// Block 256 thr = 4 waves; wave w covers o in [o0+32w, o0+32w+32), 64 p lanes.
// ---------------------------------------------------------------------------
__global__ __launch_bounds__(256) void kFuse(const float* __restrict__ mid,
                                             const float* __restrict__ Wt,
                                             const float* __restrict__ bnw,
                                             const float* __restrict__ bnb,
                                             const float* __restrict__ bnm,
                                             const float* __restrict__ bnv,
                                             float* __restrict__ out) {
    const int tid = threadIdx.x;
    const int lane = tid & 63;
    const int w = __builtin_amdgcn_readfirstlane(tid >> 6);  // 0..3, uniform
    const int p = blockIdx.x * 64 + lane;
    const int o0 = blockIdx.y * 128 + w * 32;
    const int n = blockIdx.z;

    const float* bcol = mid + (size_t)n * CC * HW_ + p;
    const float* wbase = Wt + o0;

    float acc[32];
#pragma unroll
    for (int j = 0; j < 32; ++j) acc[j] = 0.f;

#pragma unroll 2
    for (int c = 0; c < CC; ++c) {
        const float bv = bcol[(size_t)c * HW_];              // coalesced 256B
        const float* wr = wbase + (size_t)c * CC;            // uniform -> s_load
#pragma unroll
        for (int j = 0; j < 32; ++j) acc[j] = fmaf(wr[j], bv, acc[j]);
    }

#pragma unroll
    for (int j = 0; j < 32; ++j) {
        const int o = o0 + j;
        const float inv = bnw[o] / sqrtf(bnv[o] + BN_EPS);
        const float b2 = bnb[o] - bnm[o] * inv;
        const float v = fmaf(acc[j], inv, b2);
        out[((size_t)(n * CC + o)) * HW_ + p] = fmaxf(v, 0.f);
    }
}

// ---------------------------------------------------------------------------
extern "C" void kernel_launch(void* const* d_in, const int* in_sizes, int n_in,
                              void* d_out, int out_size, void* d_ws, size_t ws_size,
                              hipStream_t stream) {
    const float* cat    = (const float*)d_in[0];
    const float* stack  = (const float*)d_in[1];
    const float* w_proj = (const float*)d_in[2];
    const float* b_proj = (const float*)d_in[3];
    const float* w_fuse = (const float*)d_in[4];
    const float* bnw    = (const float*)d_in[5];
    const float* bnb    = (const float*)d_in[6];
    const float* bnm    = (const float*)d_in[7];
    const float* bnv    = (const float*)d_in[8];
    const float* gamma  = (const float*)d_in[9];
    float* outp = (float*)d_out;

    // ws layout (floats); total ~35 MB:
    float* ws  = (float*)d_ws;
    float* wT  = ws;                          // [3072][8]            24576
    float* Wt  = wT + (size_t)KK * 8;         // [512][512]          262144
    float* att = Wt + (size_t)CC * CC;        // [4][6][4096]         98304
    float* mid = att + (size_t)NN * SS * HW_; // [4][512][4096]     8388608

    kPrep<<<dim3((KK * 8 + CC * CC + 255) / 256), dim3(256), 0, stream>>>(
        w_proj, w_fuse, wT, Wt);
    kAtt<<<dim3(NP_ / 64), dim3(1024), 0, stream>>>(cat, wT, b_proj, att);
    kAggr<<<dim3(NP_ / 32), dim3(256), 0, stream>>>(stack, att, gamma, mid);
    kFuse<<<dim3(HW_ / 64, CC / 128, NN), dim3(256), 0, stream>>>(
        mid, Wt, bnw, bnb, bnm, bnv, outp);
}

// Round 5
// 569.237 us; speedup vs baseline: 1.0135x; 1.0135x over previous
//
#include <hip/hip_runtime.h>
#include <cmath>

#define NN 4
#define CC 512
#define SS 6
#define HW_ 4096
#define KK 3072
#define NP_ 16384
#define BN_EPS 1e-5f

// ---------------------------------------------------------------------------
// Prep: pack w_proj [6][3072] -> wT [3072][8] (padded); transpose w_fuse
// [o][c] -> Wt [c][o]; fold BN into binv[o], bb2[o]. Tiny.
// ---------------------------------------------------------------------------
__global__ __launch_bounds__(256) void kPrep(const float* __restrict__ w_proj,
                                             const float* __restrict__ w_fuse,
                                             const float* __restrict__ bnw,
                                             const float* __restrict__ bnb,
                                             const float* __restrict__ bnm,
                                             const float* __restrict__ bnv,
                                             float* __restrict__ wT,
                                             float* __restrict__ Wt,
                                             float* __restrict__ binv,
                                             float* __restrict__ bb2) {
    const int idx = blockIdx.x * 256 + threadIdx.x;
    if (idx < KK * 8) {
        const int k = idx >> 3, s = idx & 7;
        wT[idx] = (s < SS) ? w_proj[s * KK + k] : 0.0f;
    }
    if (idx < CC) {
        const float iv = bnw[idx] / sqrtf(bnv[idx] + BN_EPS);
        binv[idx] = iv;
        bb2[idx] = bnb[idx] - bnm[idx] * iv;
    }
    const int j = idx - KK * 8;
    if (j >= 0 && j < CC * CC) {
        const int c = j >> 9, o = j & 511;
        Wt[j] = w_fuse[o * CC + c];  // Wt[c][o]
    }
}

// ---------------------------------------------------------------------------
// Kernel A: energy[n,s,p] = sum_k cat[n,k,p]*w_proj[s,k] + b_proj[s];
//           att = softmax over s.  Block: 1024 thr = 16 kq-splits x 64 px.
// cat loads lane-coalesced (256B/instr); wT rows via wave-uniform s_loads.
// ---------------------------------------------------------------------------
__global__ __launch_bounds__(1024) void kAtt(const float* __restrict__ cat,
                                             const float* __restrict__ wT,
                                             const float* __restrict__ b_proj,
                                             float* __restrict__ att) {
    __shared__ float red[16][64][6];
    const int tid = threadIdx.x;
    const int px = tid & 63;
    const int kq = __builtin_amdgcn_readfirstlane(tid >> 6);  // 0..15, uniform
    const int pg = blockIdx.x * 64 + px;
    const int n = pg >> 12;
    const int p = pg & 4095;
    const float* cbase = cat + (size_t)n * KK * HW_ + p;

    float e[6] = {0.f, 0.f, 0.f, 0.f, 0.f, 0.f};
    const int k0 = kq * 192;
#pragma unroll 8
    for (int kk = 0; kk < 192; ++kk) {
        const int k = k0 + kk;
        const float v = cbase[(size_t)k * HW_];                      // coalesced
        const float4 wa = *(const float4*)(wT + (size_t)k * 8);      // s_load
        const float2 wb = *(const float2*)(wT + (size_t)k * 8 + 4);  // s_load
        e[0] = fmaf(wa.x, v, e[0]);
        e[1] = fmaf(wa.y, v, e[1]);
        e[2] = fmaf(wa.z, v, e[2]);
        e[3] = fmaf(wa.w, v, e[3]);
        e[4] = fmaf(wb.x, v, e[4]);
        e[5] = fmaf(wb.y, v, e[5]);
    }
#pragma unroll
    for (int s = 0; s < 6; ++s) red[kq][px][s] = e[s];
    __syncthreads();

    if (tid < 64) {
        float t[6];
#pragma unroll
        for (int s = 0; s < 6; ++s) t[s] = b_proj[s];
#pragma unroll
        for (int q = 0; q < 16; ++q)
#pragma unroll
            for (int s = 0; s < 6; ++s) t[s] += red[q][tid][s];
        float m = t[0];
#pragma unroll
        for (int s = 1; s < 6; ++s) m = fmaxf(m, t[s]);
        float ex[6];
        float sum = 0.f;
#pragma unroll
        for (int s = 0; s < 6; ++s) { ex[s] = expf(t[s] - m); sum += ex[s]; }
        const float inv = 1.0f / sum;
#pragma unroll
        for (int s = 0; s < 6; ++s)
            att[((size_t)n * 6 + s) * HW_ + p] = ex[s] * inv;  // [n][s][hw]
    }
}

// ---------------------------------------------------------------------------
// Kernel B: per pixel p:
//   pass1: o (transient) = sum_s yv[c][s]*a1[s];  e2[s] += yv[c][s]*o
//   softmax(e2) -> a2;  ab[s] = a1[s] + gamma*a2[s]
//   pass2: mid[n][c][p] = sum_s yv[c][s]*ab[s]
// Block: 512 thr = 8 cq-splits x 64 px (wave = 64 contiguous px -> every
// load instr covers one contiguous 1536B run). Each thread owns 64 c's.
// ---------------------------------------------------------------------------
__global__ __launch_bounds__(512) void kAggr(const float* __restrict__ stack,
                                             const float* __restrict__ att,
                                             const float* __restrict__ gamma,
                                             float* __restrict__ mid) {
    __shared__ float red2[8][64][6];
    __shared__ float ab_s[64][6];
    const int tid = threadIdx.x;
    const int px = tid & 63;
    const int cq = __builtin_amdgcn_readfirstlane(tid >> 6);  // 0..7, uniform
    const int pg = blockIdx.x * 64 + px;
    const int n = pg >> 12;
    const int p = pg & 4095;

    float a1[6];
#pragma unroll
    for (int s = 0; s < 6; ++s) a1[s] = att[((size_t)n * 6 + s) * HW_ + p];

    const float* sb = stack + ((size_t)(n * CC + cq * 64) * HW_ + p) * SS;

    float e2[6] = {0.f, 0.f, 0.f, 0.f, 0.f, 0.f};
#pragma unroll 4
    for (int i = 0; i < 64; ++i) {
        const float2* b2 = (const float2*)(sb + (size_t)i * (HW_ * SS));
        const float2 v01 = b2[0];
        const float2 v23 = b2[1];
        const float2 v45 = b2[2];
        float o = v01.x * a1[0];
        o = fmaf(v01.y, a1[1], o);
        o = fmaf(v23.x, a1[2], o);
        o = fmaf(v23.y, a1[3], o);
        o = fmaf(v45.x, a1[4], o);
        o = fmaf(v45.y, a1[5], o);
        e2[0] = fmaf(v01.x, o, e2[0]);
        e2[1] = fmaf(v01.y, o, e2[1]);
        e2[2] = fmaf(v23.x, o, e2[2]);
        e2[3] = fmaf(v23.y, o, e2[3]);
        e2[4] = fmaf(v45.x, o, e2[4]);
        e2[5] = fmaf(v45.y, o, e2[5]);
    }
#pragma unroll
    for (int s = 0; s < 6; ++s) red2[cq][px][s] = e2[s];
    __syncthreads();

    if (tid < 64) {
        float t[6];
#pragma unroll
        for (int s = 0; s < 6; ++s) t[s] = 0.f;
#pragma unroll
        for (int q = 0; q < 8; ++q)
#pragma unroll
            for (int s = 0; s < 6; ++s) t[s] += red2[q][tid][s];
        float m = t[0];
#pragma unroll
        for (int s = 1; s < 6; ++s) m = fmaxf(m, t[s]);
        float ex[6];
        float sum = 0.f;
#pragma unroll
        for (int s = 0; s < 6; ++s) { ex[s] = expf(t[s] - m); sum += ex[s]; }
        const float inv = gamma[0] / sum;  // fold gamma into a2
        // this thread's a1 is for pixel px=tid (cq==0 for tid<64)
#pragma unroll
        for (int s = 0; s < 6; ++s) ab_s[tid][s] = fmaf(ex[s], inv, a1[s]);
    }
    __syncthreads();

    float ab[6];
#pragma unroll
    for (int s = 0; s < 6; ++s) ab[s] = ab_s[px][s];

    float* mb = mid + (size_t)(n * CC + cq * 64) * HW_ + p;
#pragma unroll 4
    for (int i = 0; i < 64; ++i) {
        const float2* b2 = (const float2*)(sb + (size_t)i * (HW_ * SS));
        const float2 v01 = b2[0];
        const float2 v23 = b2[1];
        const float2 v45 = b2[2];
        float o = v01.x * ab[0];
        o = fmaf(v01.y, ab[1], o);
        o = fmaf(v23.x, ab[2], o);
        o = fmaf(v23.y, ab[3], o);
        o = fmaf(v45.x, ab[4], o);
        o = fmaf(v45.y, ab[5], o);
        mb[(size_t)i * HW_] = o;  // coalesced across px lanes
    }
}

// ---------------------------------------------------------------------------
// Kernel C: out[n][o][p] = relu(acc[o]*binv[o] + bb2[o]), acc = sum_c mid*W.
// f32 GEMM, LDS-free. Accumulators = 8 named float4 (guaranteed VGPRs —
// the acc[32] array version was demoted to scratch: VGPR_Count=24, 138us).
// Weights via wave-uniform s_loads; mid coalesced v-loads (L2/L3 resident).
// Block 256 thr = 4 waves; wave w covers o in [o0+32w,+32), 64 p lanes.
// ---------------------------------------------------------------------------
#define FMA4(A, W) \
    A.x = fmaf(W.x, bv, A.x); A.y = fmaf(W.y, bv, A.y); \
    A.z = fmaf(W.z, bv, A.z); A.w = fmaf(W.w, bv, A.w);

#define STORE4(A, q) { \
    const float4 iv = *(const float4*)(binv + o0 + (q) * 4); \
    const float4 bb = *(const float4*)(bb2 + o0 + (q) * 4); \
    float* ob = out + ((size_t)(n * CC + o0 + (q) * 4)) * HW_ + p; \
    ob[0 * HW_] = fmaxf(fmaf(A.x, iv.x, bb.x), 0.f); \
    ob[1 * HW_] = fmaxf(fmaf(A.y, iv.y, bb.y), 0.f); \
    ob[2 * HW_] = fmaxf(fmaf(A.z, iv.z, bb.z), 0.f); \
    ob[3 * HW_] = fmaxf(fmaf(A.w, iv.w, bb.w), 0.f); }

__global__ __launch_bounds__(256) void kFuse(const float* __restrict__ mid,
                                             const float* __restrict__ Wt,
                                             const float* __restrict__ binv,
                                             const float* __restrict__ bb2,
                                             float* __restrict__ out) {
    const int tid = threadIdx.x;
    const int lane = tid & 63;
    const int w = __builtin_amdgcn_readfirstlane(tid >> 6);  // 0..3, uniform
    const int p = blockIdx.x * 64 + lane;
    const int o0 = blockIdx.y * 128 + w * 32;
    const int n = blockIdx.z;

    const float* bcol = mid + (size_t)n * CC * HW_ + p;
    const float* wbase = Wt + o0;

    float4 A0 = {0.f, 0.f, 0.f, 0.f}, A1 = A0, A2 = A0, A3 = A0;
    float4 A4 = A0, A5 = A0, A6 = A0, A7 = A0;

#pragma unroll 2
    for (int c = 0; c < CC; ++c) {
        const float bv = bcol[(size_t)c * HW_];              // coalesced 256B
        const float4* wr = (const float4*)(wbase + (size_t)c * CC);  // s_load x8
        const float4 w0 = wr[0], w1 = wr[1], w2 = wr[2], w3 = wr[3];
        const float4 w4 = wr[4], w5 = wr[5], w6 = wr[6], w7 = wr[7];
        FMA4(A0, w0) FMA4(A1, w1) FMA4(A2, w2) FMA4(A3, w3)
        FMA4(A4, w4) FMA4(A5, w5) FMA4(A6, w6) FMA4(A7, w7)
    }

    STORE4(A0, 0) STORE4(A1, 1) STORE4(A2, 2) STORE4(A3, 3)
    STORE4(A4, 4) STORE4(A5, 5) STORE4(A6, 6) STORE4(A7, 7)
}

// ---------------------------------------------------------------------------
extern "C" void kernel_launch(void* const* d_in, const int* in_sizes, int n_in,
                              void* d_out, int out_size, void* d_ws, size_t ws_size,
                              hipStream_t stream) {
    const float* cat    = (const float*)d_in[0];
    const float* stack  = (const float*)d_in[1];
    const float* w_proj = (const float*)d_in[2];
    const float* b_proj = (const float*)d_in[3];
    const float* w_fuse = (const float*)d_in[4];
    const float* bnw    = (const float*)d_in[5];
    const float* bnb    = (const float*)d_in[6];
    const float* bnm    = (const float*)d_in[7];
    const float* bnv    = (const float*)d_in[8];
    const float* gamma  = (const float*)d_in[9];
    float* outp = (float*)d_out;

    // ws layout (floats); total ~35 MB:
    float* ws   = (float*)d_ws;
    float* wT   = ws;                           // [3072][8]           24576
    float* Wt   = wT + (size_t)KK * 8;          // [512][512]         262144
    float* binv = Wt + (size_t)CC * CC;         // [512]
    float* bb2  = binv + CC;                    // [512]
    float* att  = bb2 + CC;                     // [4][6][4096]        98304
    float* mid  = att + (size_t)NN * SS * HW_;  // [4][512][4096]    8388608

    kPrep<<<dim3((KK * 8 + CC * CC + 255) / 256), dim3(256), 0, stream>>>(
        w_proj, w_fuse, bnw, bnb, bnm, bnv, wT, Wt, binv, bb2);
    kAtt<<<dim3(NP_ / 64), dim3(1024), 0, stream>>>(cat, wT, b_proj, att);
    kAggr<<<dim3(NP_ / 64), dim3(512), 0, stream>>>(stack, att, gamma, mid);
    kFuse<<<dim3(HW_ / 64, CC / 128, NN), dim3(256), 0, stream>>>(
        mid, Wt, binv, bb2, outp);
}